// Round 14
// baseline (149.083 us; speedup 1.0000x reference)
//
#include <hip/hip_runtime.h>
#include <hip/hip_bf16.h>

#define N_NODES 50000
#define N_EDGES 800000
#define D 64
#define NB 391        // coarse buckets: dst>>7 -> 0..390 (128 nodes/bucket)
#define CHUNK_E 2048  // edges per partition block
#define NPB 391       // ceil(800000/2048)
#define NSTRIP 3125   // N_NODES/16
#define GEMM_BLKS 782 // ceil(3125/4)

typedef __attribute__((ext_vector_type(8))) short short8v;   // 8 bf16 (4 VGPRs)
typedef __attribute__((ext_vector_type(4))) float float4v;   // 4 fp32 acc

// ---------- helpers ----------
__device__ __forceinline__ float b2f(unsigned short h) {
    return __uint_as_float(((unsigned)h) << 16);
}
__device__ __forceinline__ unsigned short f2b(float f) {
    __hip_bfloat16 t = __float2bfloat16(f);
    return *reinterpret_cast<unsigned short*>(&t);
}
__device__ __forceinline__ short f2bs(float f) { return (short)f2b(f); }
// monotonic float<->uint encoding: unsigned min == float min
__device__ __forceinline__ unsigned f2ord(float f) {
    unsigned u = __float_as_uint(f);
    return (u & 0x80000000u) ? ~u : (u | 0x80000000u);
}
__device__ __forceinline__ float ord2f(unsigned o) {
    return __uint_as_float((o & 0x80000000u) ? (o ^ 0x80000000u) : ~o);
}

// ---------- kernel 1: fused [setup (last block) ∥ coarse dst histogram] -----
// blocks 0..NPB-1: per-block idx64 self-detect + LDS histogram of dst>>7
// block NPB: dtype detect -> flags, W -> bf16 W^T frag order, bias sums
// (c_cnt zeroed by memsetAsync beforehand)
__global__ __launch_bounds__(256)
void setup_hist(const void* __restrict__ featv, const void* __restrict__ srcv,
                const void* __restrict__ dstv,
                const void* __restrict__ Wtv, const void* __restrict__ btv,
                const void* __restrict__ Wpv, const void* __restrict__ bpv,
                unsigned* __restrict__ flags, unsigned* __restrict__ c_cnt,
                unsigned short* __restrict__ WTfrag, unsigned short* __restrict__ WPfrag,
                float* __restrict__ bias_sum) {
    const int t = threadIdx.x;
    if (blockIdx.x == NPB) {
        // ---- setup branch ----
        __shared__ unsigned sf[2];
        if (t < 64) {
            const unsigned short* p = (const unsigned short*)featv;
            float x = b2f(p[2 * t]);
            float a = fabsf(x);
            bool insane = !(a <= 64.f) || (x != 0.f && a < 9.3132e-10f);
            unsigned long long m = __ballot(insane);
            if (t == 0) sf[0] = (__popcll(m) >= 8) ? 1u : 0u;
        } else if (t < 128) {
            const int* s32 = (const int*)srcv;
            int v = s32[2 * (t - 64) + 1];
            unsigned long long m = __ballot(v == 0);
            if (t == 64) sf[1] = (__popcll(m) >= 32) ? 1u : 0u;
        }
        __syncthreads();
        const unsigned fp32mode = sf[0];
        if (t < 2) flags[t] = sf[t];
#pragma unroll
        for (int i = 0; i < 16; ++i) {
            int e = i * 256 + t;                       // coalesced read
            int k = e >> 6, n = e & 63;
            float vt, vp;
            if (fp32mode) {
                vt = ((const float*)Wtv)[e];
                vp = ((const float*)Wpv)[e];
            } else {
                vt = b2f(((const unsigned short*)Wtv)[e]);
                vp = b2f(((const unsigned short*)Wpv)[e]);
            }
            WTfrag[n * 64 + k] = f2b(vt);
            WPfrag[n * 64 + k] = f2b(vp);
        }
        if (t < 64) {
            if (fp32mode)
                bias_sum[t] = ((const float*)btv)[t] + ((const float*)bpv)[t];
            else
                bias_sum[t] = b2f(((const unsigned short*)btv)[t])
                            + b2f(((const unsigned short*)bpv)[t]);
        }
    } else {
        // ---- histogram branch, idx64 self-detected ----
        __shared__ unsigned cnt[NB];
        __shared__ unsigned sidx;
        if (t < 64) {
            const int* s32 = (const int*)dstv;         // probe dst itself
            int v = s32[2 * t + 1];
            unsigned long long m = __ballot(v == 0);
            if (t == 0) sidx = (__popcll(m) >= 32) ? 1u : 0u;
        }
        for (int i = t; i < NB; i += 256) cnt[i] = 0;
        __syncthreads();
        const unsigned idx64 = sidx;
        const int base = blockIdx.x * CHUNK_E;
#pragma unroll
        for (int j = 0; j < CHUNK_E / 256; ++j) {
            int e = base + j * 256 + t;
            if (e < N_EDGES) {
                int d = idx64 ? (int)((const long long*)dstv)[e] : ((const int*)dstv)[e];
                d = min(max(d, 0), N_NODES - 1);
                atomicAdd(&cnt[d >> 7], 1u);
            }
        }
        __syncthreads();
        for (int i = t; i < NB; i += 256)
            if (cnt[i]) atomicAdd(&c_cnt[i], cnt[i]);
    }
}

// ---------- kernel 2: scan of NB coarse counts -> c_off, c_cur ----------
__global__ __launch_bounds__(512)
void scanNB(const unsigned* __restrict__ c_cnt, unsigned* __restrict__ c_off,
            unsigned* __restrict__ c_cur) {
    __shared__ unsigned sm[512];
    const int t = threadIdx.x;
    unsigned v = (t < NB) ? c_cnt[t] : 0u;
    sm[t] = v;
    __syncthreads();
    for (int off = 1; off < 512; off <<= 1) {
        unsigned u = (t >= off) ? sm[t - off] : 0u;
        __syncthreads();
        sm[t] += u;
        __syncthreads();
    }
    if (t < NB) { c_off[t] = sm[t] - v; c_cur[t] = sm[t] - v; }
    if (t == 0) c_off[NB] = N_EDGES;
}

// ---------- kernel 3: fused [MFMA node transforms ∥ coarse partition] ----------
__global__ __launch_bounds__(256)
void gemm_scatter(const void* __restrict__ featv,
                  const unsigned short* __restrict__ WTfrag,
                  const unsigned short* __restrict__ WPfrag,
                  const float* __restrict__ bias_sum,
                  const void* __restrict__ srcv, const void* __restrict__ dstv,
                  const unsigned* __restrict__ flags,
                  unsigned* __restrict__ c_cur, unsigned* __restrict__ packed,
                  unsigned short* __restrict__ T16, void* __restrict__ outv) {
    const unsigned fp32mode = flags[0];
    if (blockIdx.x < GEMM_BLKS) {
        const int lane = threadIdx.x & 63;
        const int wid  = threadIdx.x >> 6;
        const int w = blockIdx.x * 4 + wid;            // one 16-row strip per wave
        if (w >= NSTRIP) return;
        const int m = lane & 15, q = lane >> 4;

        short8v A0, A1;
        if (fp32mode) {
            const float* fr = (const float*)featv + (w * 16 + m) * D + q * 8;
            float4 l0 = *(const float4*)(fr);
            float4 h0 = *(const float4*)(fr + 4);
            float4 l1 = *(const float4*)(fr + 32);
            float4 h1 = *(const float4*)(fr + 36);
            A0 = (short8v){f2bs(l0.x), f2bs(l0.y), f2bs(l0.z), f2bs(l0.w),
                           f2bs(h0.x), f2bs(h0.y), f2bs(h0.z), f2bs(h0.w)};
            A1 = (short8v){f2bs(l1.x), f2bs(l1.y), f2bs(l1.z), f2bs(l1.w),
                           f2bs(h1.x), f2bs(h1.y), f2bs(h1.z), f2bs(h1.w)};
        } else {
            const short* fr = (const short*)featv + (w * 16 + m) * D + q * 8;
            A0 = *(const short8v*)fr;
            A1 = *(const short8v*)(fr + 32);
        }

        const short8v* BT = (const short8v*)WTfrag;    // idx = col*8 + h*4 + q
        const short8v* BP = (const short8v*)WPfrag;
        float* Cf  = (float*)outv;
        unsigned short* Ch = (unsigned short*)outv;

#pragma unroll
        for (int c = 0; c < 4; ++c) {
            const int col = 16 * c + m;
            short8v Bt0 = BT[col * 8 + q];
            short8v Bt1 = BT[col * 8 + 4 + q];
            short8v Bp0 = BP[col * 8 + q];
            short8v Bp1 = BP[col * 8 + 4 + q];
            float bs = bias_sum[col];
            float4v accT = (float4v){0.f, 0.f, 0.f, 0.f};
            float4v accP = (float4v){bs, bs, bs, bs};
            accT = __builtin_amdgcn_mfma_f32_16x16x32_bf16(A0, Bt0, accT, 0, 0, 0);
            accT = __builtin_amdgcn_mfma_f32_16x16x32_bf16(A1, Bt1, accT, 0, 0, 0);
            accP = __builtin_amdgcn_mfma_f32_16x16x32_bf16(A0, Bp0, accP, 0, 0, 0);
            accP = __builtin_amdgcn_mfma_f32_16x16x32_bf16(A1, Bp1, accP, 0, 0, 0);
            // C/D layout: col = lane&15 (+16c), row = q*4 + reg
#pragma unroll
            for (int r = 0; r < 4; ++r) {
                const int row = w * 16 + q * 4 + r;
                T16[row * D + col] = f2b(accT[r]);
                if (fp32mode) Cf[row * D + col] = accT[r] + accP[r];
                else          Ch[row * D + col] = f2b(accT[r] + accP[r]);
            }
        }
    } else {
        // ---- coarse partition branch ----
        __shared__ unsigned h[NB];
        const int t = threadIdx.x;
        for (int i = t; i < NB; i += 256) h[i] = 0;
        __syncthreads();
        const unsigned idx64 = flags[1];
        const int base = (blockIdx.x - GEMM_BLKS) * CHUNK_E;
        unsigned pk[CHUNK_E / 256];
#pragma unroll
        for (int j = 0; j < CHUNK_E / 256; ++j) {
            int e = base + j * 256 + t;
            unsigned p = 0xFFFFFFFFu;                  // sentinel
            if (e < N_EDGES) {
                int s, d;
                if (idx64) {
                    s = (int)((const long long*)srcv)[e];
                    d = (int)((const long long*)dstv)[e];
                } else {
                    s = ((const int*)srcv)[e];
                    d = ((const int*)dstv)[e];
                }
                s = min(max(s, 0), N_NODES - 1);
                d = min(max(d, 0), N_NODES - 1);
                p = ((unsigned)d << 16) | (unsigned)s;
                atomicAdd(&h[d >> 7], 1u);
            }
            pk[j] = p;
        }
        __syncthreads();
        // one reservation atomic per (block,bucket); h becomes the LDS cursor
        for (int i = t; i < NB; i += 256) h[i] = atomicAdd(&c_cur[i], h[i]);
        __syncthreads();
#pragma unroll
        for (int j = 0; j < CHUNK_E / 256; ++j) {
            unsigned p = pk[j];
            if (p != 0xFFFFFFFFu) {
                unsigned pos = atomicAdd(&h[p >> 23], 1u); // p>>23 == dst>>7
                packed[pos] = p;
            }
        }
    }
}

// ---------- kernel 4: per-bucket LDS min (read-before-atomic) + epilogue ----
// One block per bucket of 128 nodes. mn[128][64] ord-u32 minima in LDS (32 KB).
// ds_read_b128 the current quad; predicated atomicMin only on improvement
// (stale reads are conservative-safe: mn only decreases).
__global__ __launch_bounds__(512)
void bucket_min(const unsigned* __restrict__ c_off, const unsigned* __restrict__ packed,
                const unsigned short* __restrict__ T16, const unsigned* __restrict__ flags,
                void* __restrict__ outv) {
    __shared__ unsigned mn[128 * 64];                  // 32 KB
    const unsigned fp32mode = flags[0];
    const int t = threadIdx.x;
    const int b = blockIdx.x;
#pragma unroll
    for (int i = 0; i < 16; ++i) mn[i * 512 + t] = 0xFFFFFFFFu;
    __syncthreads();
    const int estart = (int)c_off[b], eend = (int)c_off[b + 1];
    const int lane = t & 63, wv = t >> 6;              // 8 waves
    const int g = lane >> 4, fb = (lane & 15) << 2;    // 4 edges x 16 feature-quads
    int i = estart + wv * 4 + g;
    for (; i + 32 < eend; i += 64) {                   // 2 gathers in flight
        unsigned p0 = packed[i], p1 = packed[i + 32];
        uint2 v0 = *(const uint2*)(T16 + (int)(p0 & 0xFFFFu) * D + fb);
        uint2 v1 = *(const uint2*)(T16 + (int)(p1 & 0xFFFFu) * D + fb);
        unsigned* m0p = &mn[(int)((p0 >> 16) & 127u) * 64 + fb];
        unsigned* m1p = &mn[(int)((p1 >> 16) & 127u) * 64 + fb];
        uint4 c0 = *(const uint4*)m0p;                 // ds_read_b128
        uint4 c1 = *(const uint4*)m1p;
        unsigned e0 = f2ord(b2f((unsigned short)v0.x));
        unsigned e1 = f2ord(b2f((unsigned short)(v0.x >> 16)));
        unsigned e2 = f2ord(b2f((unsigned short)v0.y));
        unsigned e3 = f2ord(b2f((unsigned short)(v0.y >> 16)));
        if (e0 < c0.x) atomicMin(m0p + 0, e0);
        if (e1 < c0.y) atomicMin(m0p + 1, e1);
        if (e2 < c0.z) atomicMin(m0p + 2, e2);
        if (e3 < c0.w) atomicMin(m0p + 3, e3);
        unsigned f0 = f2ord(b2f((unsigned short)v1.x));
        unsigned f1 = f2ord(b2f((unsigned short)(v1.x >> 16)));
        unsigned f2 = f2ord(b2f((unsigned short)v1.y));
        unsigned f3 = f2ord(b2f((unsigned short)(v1.y >> 16)));
        if (f0 < c1.x) atomicMin(m1p + 0, f0);
        if (f1 < c1.y) atomicMin(m1p + 1, f1);
        if (f2 < c1.z) atomicMin(m1p + 2, f2);
        if (f3 < c1.w) atomicMin(m1p + 3, f3);
    }
    for (; i < eend; i += 32) {
        unsigned p0 = packed[i];
        uint2 v0 = *(const uint2*)(T16 + (int)(p0 & 0xFFFFu) * D + fb);
        unsigned* m0p = &mn[(int)((p0 >> 16) & 127u) * 64 + fb];
        uint4 c0 = *(const uint4*)m0p;
        unsigned e0 = f2ord(b2f((unsigned short)v0.x));
        unsigned e1 = f2ord(b2f((unsigned short)(v0.x >> 16)));
        unsigned e2 = f2ord(b2f((unsigned short)v0.y));
        unsigned e3 = f2ord(b2f((unsigned short)(v0.y >> 16)));
        if (e0 < c0.x) atomicMin(m0p + 0, e0);
        if (e1 < c0.y) atomicMin(m0p + 1, e1);
        if (e2 < c0.z) atomicMin(m0p + 2, e2);
        if (e3 < c0.w) atomicMin(m0p + 3, e3);
    }
    __syncthreads();
    // epilogue: 128 nodes x 16 float4-quads = 2048 slots
    const int node0 = b << 7;
    for (int sl = t; sl < 128 * 16; sl += 512) {
        const int row = sl >> 4;
        const int node = node0 + row;
        if (node >= N_NODES) break;                    // sl monotone per thread
        const int f4 = (sl & 15) << 2;
        const unsigned* mp = &mn[row * 64 + f4];
        float m0 = ord2f(mp[0]), m1 = ord2f(mp[1]);
        float m2 = ord2f(mp[2]), m3 = ord2f(mp[3]);
        if (fp32mode) {
            float4* C = (float4*)((float*)outv + node * D + f4);
            float4 c = *C;
            *C = make_float4(c.x - m0, c.y - m1, c.z - m2, c.w - m3);
        } else {
            unsigned short* C = (unsigned short*)outv + node * D + f4;
            uint2 c = *(uint2*)C;
            unsigned lo = (unsigned)f2b(b2f((unsigned short)c.x) - m0)
                        | ((unsigned)f2b(b2f((unsigned short)(c.x >> 16)) - m1) << 16);
            unsigned hi = (unsigned)f2b(b2f((unsigned short)c.y) - m2)
                        | ((unsigned)f2b(b2f((unsigned short)(c.y >> 16)) - m3) << 16);
            *(uint2*)C = make_uint2(lo, hi);
        }
    }
}

extern "C" void kernel_launch(void* const* d_in, const int* in_sizes, int n_in,
                              void* d_out, int out_size, void* d_ws, size_t ws_size,
                              hipStream_t stream) {
    // ws layout (~9.6 MB used):
    char* p = (char*)d_ws;
    unsigned*       flags    = (unsigned*)p;                     // 256 B
    unsigned*       c_cnt    = (unsigned*)(p + 256);             // 392*4 -> 2048
    unsigned*       c_off    = (unsigned*)(p + 2304);            // 2048
    unsigned*       c_cur    = (unsigned*)(p + 4352);            // 2048
    unsigned*       packed   = (unsigned*)(p + 6400);            // 3.2 MB
    unsigned short* T16      = (unsigned short*)(p + 6400 + 3200000);   // 6.4 MB
    unsigned short* WTfrag   = (unsigned short*)(p + 6400 + 3200000 + 6400000);        // 8 KB
    unsigned short* WPfrag   = (unsigned short*)(p + 6400 + 3200000 + 6400000 + 8192); // 8 KB
    float*          bias_sum = (float*)(p + 6400 + 3200000 + 6400000 + 16384);         // 256 B

    hipMemsetAsync(c_cnt, 0, NB * sizeof(unsigned), stream);
    setup_hist<<<NPB + 1, 256, 0, stream>>>(d_in[0], d_in[1], d_in[2],
                                            d_in[3], d_in[4], d_in[5], d_in[6],
                                            flags, c_cnt, WTfrag, WPfrag, bias_sum);
    scanNB<<<1, 512, 0, stream>>>(c_cnt, c_off, c_cur);
    gemm_scatter<<<GEMM_BLKS + NPB, 256, 0, stream>>>(d_in[0], WTfrag, WPfrag, bias_sum,
                                                      d_in[1], d_in[2], flags,
                                                      c_cur, packed, T16, d_out);
    bucket_min<<<NB, 512, 0, stream>>>(c_off, packed, T16, flags, d_out);
}

// Round 15
// 135.651 us; speedup vs baseline: 1.0990x; 1.0990x over previous
//
#include <hip/hip_runtime.h>
#include <hip/hip_bf16.h>

#define N_NODES 50000
#define N_EDGES 800000
#define D 64
#define NB 391        // coarse buckets: dst>>7 -> 0..390 (128 nodes/bucket)
#define BCAP 4096     // fixed slots per bucket region (max load ~2100)
#define CHUNK_E 2048  // edges per scatter block
#define NSC 391       // ceil(800000/2048)
#define NSTRIP 3125   // N_NODES/16
#define GEMM_BLKS 782 // ceil(3125/4)

typedef __attribute__((ext_vector_type(8))) short short8v;   // 8 bf16 (4 VGPRs)
typedef __attribute__((ext_vector_type(4))) float float4v;   // 4 fp32 acc

// ---------- helpers ----------
__device__ __forceinline__ float b2f(unsigned short h) {
    return __uint_as_float(((unsigned)h) << 16);
}
__device__ __forceinline__ unsigned short f2b(float f) {
    __hip_bfloat16 t = __float2bfloat16(f);
    return *reinterpret_cast<unsigned short*>(&t);
}
__device__ __forceinline__ short f2bs(float f) { return (short)f2b(f); }
// monotonic float<->uint encoding: unsigned min == float min
__device__ __forceinline__ unsigned f2ord(float f) {
    unsigned u = __float_as_uint(f);
    return (u & 0x80000000u) ? ~u : (u | 0x80000000u);
}
__device__ __forceinline__ float ord2f(unsigned o) {
    return __uint_as_float((o & 0x80000000u) ? (o ^ 0x80000000u) : ~o);
}

// ---------- kernel 1: setup (1 block): flags, W->bf16 W^T frags, bias ------
__global__ __launch_bounds__(256)
void setup(const void* __restrict__ featv, const void* __restrict__ srcv,
           const void* __restrict__ Wtv, const void* __restrict__ btv,
           const void* __restrict__ Wpv, const void* __restrict__ bpv,
           unsigned* __restrict__ flags,
           unsigned short* __restrict__ WTfrag, unsigned short* __restrict__ WPfrag,
           float* __restrict__ bias_sum) {
    __shared__ unsigned sf[2];
    const int t = threadIdx.x;
    if (t < 64) {
        const unsigned short* p = (const unsigned short*)featv;
        float x = b2f(p[2 * t]);
        float a = fabsf(x);
        bool insane = !(a <= 64.f) || (x != 0.f && a < 9.3132e-10f);
        unsigned long long m = __ballot(insane);
        if (t == 0) sf[0] = (__popcll(m) >= 8) ? 1u : 0u;
    } else if (t < 128) {
        const int* s32 = (const int*)srcv;
        int v = s32[2 * (t - 64) + 1];
        unsigned long long m = __ballot(v == 0);
        if (t == 64) sf[1] = (__popcll(m) >= 32) ? 1u : 0u;
    }
    __syncthreads();
    const unsigned fp32mode = sf[0];
    if (t < 2) flags[t] = sf[t];
#pragma unroll
    for (int i = 0; i < 16; ++i) {
        int e = i * 256 + t;                           // coalesced read
        int k = e >> 6, n = e & 63;
        float vt, vp;
        if (fp32mode) {
            vt = ((const float*)Wtv)[e];
            vp = ((const float*)Wpv)[e];
        } else {
            vt = b2f(((const unsigned short*)Wtv)[e]);
            vp = b2f(((const unsigned short*)Wpv)[e]);
        }
        WTfrag[n * 64 + k] = f2b(vt);                  // Wfrag[n*64+k] = W[k][n]
        WPfrag[n * 64 + k] = f2b(vp);
    }
    if (t < 64) {
        if (fp32mode)
            bias_sum[t] = ((const float*)btv)[t] + ((const float*)bpv)[t];
        else
            bias_sum[t] = b2f(((const unsigned short*)btv)[t])
                        + b2f(((const unsigned short*)bpv)[t]);
    }
}

// ---------- kernel 2: fused [MFMA node transforms ∥ bucket append] ----------
// blocks [0, GEMM_BLKS): T=feat@Wt -> T16 ; C=feat@(Wt+Wp)+b -> d_out
// blocks [GEMM_BLKS, +NSC): append (dst<<16|src) into fixed-stride bucket
//   regions packed[b*BCAP ...] via per-(block,bucket) cursor reservation.
//   No histogram or scan pass needed. Self-loops dropped (seeded in k3).
__global__ __launch_bounds__(256)
void gemm_scatter(const void* __restrict__ featv,
                  const unsigned short* __restrict__ WTfrag,
                  const unsigned short* __restrict__ WPfrag,
                  const float* __restrict__ bias_sum,
                  const void* __restrict__ srcv, const void* __restrict__ dstv,
                  const unsigned* __restrict__ flags,
                  unsigned* __restrict__ c_cur, unsigned* __restrict__ packed,
                  unsigned short* __restrict__ T16, void* __restrict__ outv) {
    const unsigned fp32mode = flags[0];
    if (blockIdx.x < GEMM_BLKS) {
        const int lane = threadIdx.x & 63;
        const int wid  = threadIdx.x >> 6;
        const int w = blockIdx.x * 4 + wid;            // one 16-row strip per wave
        if (w >= NSTRIP) return;
        const int m = lane & 15, q = lane >> 4;

        short8v A0, A1;                                // A[m][k=q*8+j], k-halves
        if (fp32mode) {
            const float* fr = (const float*)featv + (w * 16 + m) * D + q * 8;
            float4 l0 = *(const float4*)(fr);
            float4 h0 = *(const float4*)(fr + 4);
            float4 l1 = *(const float4*)(fr + 32);
            float4 h1 = *(const float4*)(fr + 36);
            A0 = (short8v){f2bs(l0.x), f2bs(l0.y), f2bs(l0.z), f2bs(l0.w),
                           f2bs(h0.x), f2bs(h0.y), f2bs(h0.z), f2bs(h0.w)};
            A1 = (short8v){f2bs(l1.x), f2bs(l1.y), f2bs(l1.z), f2bs(l1.w),
                           f2bs(h1.x), f2bs(h1.y), f2bs(h1.z), f2bs(h1.w)};
        } else {
            const short* fr = (const short*)featv + (w * 16 + m) * D + q * 8;
            A0 = *(const short8v*)fr;
            A1 = *(const short8v*)(fr + 32);
        }

        const short8v* BT = (const short8v*)WTfrag;    // idx = col*8 + h*4 + q
        const short8v* BP = (const short8v*)WPfrag;
        float* Cf  = (float*)outv;
        unsigned short* Ch = (unsigned short*)outv;

#pragma unroll
        for (int c = 0; c < 4; ++c) {
            const int col = 16 * c + m;
            short8v Bt0 = BT[col * 8 + q];
            short8v Bt1 = BT[col * 8 + 4 + q];
            short8v Bp0 = BP[col * 8 + q];
            short8v Bp1 = BP[col * 8 + 4 + q];
            float bs = bias_sum[col];
            float4v accT = (float4v){0.f, 0.f, 0.f, 0.f};
            float4v accP = (float4v){bs, bs, bs, bs};
            accT = __builtin_amdgcn_mfma_f32_16x16x32_bf16(A0, Bt0, accT, 0, 0, 0);
            accT = __builtin_amdgcn_mfma_f32_16x16x32_bf16(A1, Bt1, accT, 0, 0, 0);
            accP = __builtin_amdgcn_mfma_f32_16x16x32_bf16(A0, Bp0, accP, 0, 0, 0);
            accP = __builtin_amdgcn_mfma_f32_16x16x32_bf16(A1, Bp1, accP, 0, 0, 0);
            // C/D layout: col = lane&15 (+16c), row = q*4 + reg
#pragma unroll
            for (int r = 0; r < 4; ++r) {
                const int row = w * 16 + q * 4 + r;
                T16[row * D + col] = f2b(accT[r]);
                if (fp32mode) Cf[row * D + col] = accT[r] + accP[r];
                else          Ch[row * D + col] = f2b(accT[r] + accP[r]);
            }
        }
    } else {
        // ---- bucket append branch ----
        __shared__ unsigned h[NB];
        const int t = threadIdx.x;
        for (int i = t; i < NB; i += 256) h[i] = 0;
        __syncthreads();
        const unsigned idx64 = flags[1];
        const int base = (blockIdx.x - GEMM_BLKS) * CHUNK_E;
        unsigned pk[CHUNK_E / 256];
#pragma unroll
        for (int j = 0; j < CHUNK_E / 256; ++j) {
            int e = base + j * 256 + t;
            unsigned p = 0xFFFFFFFFu;                  // sentinel
            if (e < N_EDGES) {
                int s, d;
                if (idx64) {
                    s = (int)((const long long*)srcv)[e];
                    d = (int)((const long long*)dstv)[e];
                } else {
                    s = ((const int*)srcv)[e];
                    d = ((const int*)dstv)[e];
                }
                s = min(max(s, 0), N_NODES - 1);
                d = min(max(d, 0), N_NODES - 1);
                if (s != d) {                          // self-loops seeded in k3
                    p = ((unsigned)d << 16) | (unsigned)s;
                    atomicAdd(&h[d >> 7], 1u);
                }
            }
            pk[j] = p;
        }
        __syncthreads();
        // one reservation atomic per (block,bucket); h becomes the LDS cursor
        for (int i = t; i < NB; i += 256) h[i] = atomicAdd(&c_cur[i], h[i]);
        __syncthreads();
#pragma unroll
        for (int j = 0; j < CHUNK_E / 256; ++j) {
            unsigned p = pk[j];
            if (p != 0xFFFFFFFFu) {
                unsigned bkt = p >> 23;                // == dst>>7
                unsigned pos = atomicAdd(&h[bkt], 1u);
                if (pos < BCAP)                        // overflow guard (never hits)
                    packed[bkt * BCAP + pos] = p;
            }
        }
    }
}

// ---------- kernel 3: per-bucket LDS-atomic min + fused epilogue ----------
// One block per bucket of 128 nodes. mn[128][64] ord-u32 minima in LDS (32 KB),
// seeded with each node's own T row (covers self-loops). 4 gathers in flight,
// unconditional LDS atomicMin (r13 structure — r14's read-first regressed).
__global__ __launch_bounds__(512)
void bucket_min(const unsigned* __restrict__ c_cur, const unsigned* __restrict__ packed,
                const unsigned short* __restrict__ T16, const unsigned* __restrict__ flags,
                void* __restrict__ outv) {
    __shared__ unsigned mn[128 * 64];                  // 32 KB
    const unsigned fp32mode = flags[0];
    const int t = threadIdx.x;
    const int b = blockIdx.x;
    const int node0 = b << 7;
    // seed with own-node T rows (coalesced 16 KB; covers self-loop edges)
    for (int sl = t; sl < 128 * 16; sl += 512) {
        const int row = sl >> 4;
        const int f4 = (sl & 15) << 2;
        unsigned* mp = &mn[row * 64 + f4];
        if (node0 + row < N_NODES) {
            uint2 v = *(const uint2*)(T16 + (node0 + row) * D + f4);
            mp[0] = f2ord(b2f((unsigned short)v.x));
            mp[1] = f2ord(b2f((unsigned short)(v.x >> 16)));
            mp[2] = f2ord(b2f((unsigned short)v.y));
            mp[3] = f2ord(b2f((unsigned short)(v.y >> 16)));
        } else {
            mp[0] = mp[1] = mp[2] = mp[3] = 0xFFFFFFFFu;
        }
    }
    __syncthreads();
    const int cnt = min((int)c_cur[b], BCAP);
    const unsigned* pb = packed + b * BCAP;
    const int lane = t & 63, wv = t >> 6;              // 8 waves
    const int g = lane >> 4, fb = (lane & 15) << 2;    // 4 edges x 16 feature-quads
    int i = wv * 4 + g;
    for (; i + 96 < cnt; i += 128) {                   // 4 gathers in flight
        unsigned p0 = pb[i],      p1 = pb[i + 32];
        unsigned p2 = pb[i + 64], p3 = pb[i + 96];
        uint2 v0 = *(const uint2*)(T16 + (int)(p0 & 0xFFFFu) * D + fb);
        uint2 v1 = *(const uint2*)(T16 + (int)(p1 & 0xFFFFu) * D + fb);
        uint2 v2 = *(const uint2*)(T16 + (int)(p2 & 0xFFFFu) * D + fb);
        uint2 v3 = *(const uint2*)(T16 + (int)(p3 & 0xFFFFu) * D + fb);
        unsigned* m0p = &mn[(int)((p0 >> 16) & 127u) * 64 + fb];
        unsigned* m1p = &mn[(int)((p1 >> 16) & 127u) * 64 + fb];
        unsigned* m2p = &mn[(int)((p2 >> 16) & 127u) * 64 + fb];
        unsigned* m3p = &mn[(int)((p3 >> 16) & 127u) * 64 + fb];
        atomicMin(m0p + 0, f2ord(b2f((unsigned short)v0.x)));
        atomicMin(m0p + 1, f2ord(b2f((unsigned short)(v0.x >> 16))));
        atomicMin(m0p + 2, f2ord(b2f((unsigned short)v0.y)));
        atomicMin(m0p + 3, f2ord(b2f((unsigned short)(v0.y >> 16))));
        atomicMin(m1p + 0, f2ord(b2f((unsigned short)v1.x)));
        atomicMin(m1p + 1, f2ord(b2f((unsigned short)(v1.x >> 16))));
        atomicMin(m1p + 2, f2ord(b2f((unsigned short)v1.y)));
        atomicMin(m1p + 3, f2ord(b2f((unsigned short)(v1.y >> 16))));
        atomicMin(m2p + 0, f2ord(b2f((unsigned short)v2.x)));
        atomicMin(m2p + 1, f2ord(b2f((unsigned short)(v2.x >> 16))));
        atomicMin(m2p + 2, f2ord(b2f((unsigned short)v2.y)));
        atomicMin(m2p + 3, f2ord(b2f((unsigned short)(v2.y >> 16))));
        atomicMin(m3p + 0, f2ord(b2f((unsigned short)v3.x)));
        atomicMin(m3p + 1, f2ord(b2f((unsigned short)(v3.x >> 16))));
        atomicMin(m3p + 2, f2ord(b2f((unsigned short)v3.y)));
        atomicMin(m3p + 3, f2ord(b2f((unsigned short)(v3.y >> 16))));
    }
    for (; i < cnt; i += 32) {
        unsigned p0 = pb[i];
        uint2 v0 = *(const uint2*)(T16 + (int)(p0 & 0xFFFFu) * D + fb);
        unsigned* m0p = &mn[(int)((p0 >> 16) & 127u) * 64 + fb];
        atomicMin(m0p + 0, f2ord(b2f((unsigned short)v0.x)));
        atomicMin(m0p + 1, f2ord(b2f((unsigned short)(v0.x >> 16))));
        atomicMin(m0p + 2, f2ord(b2f((unsigned short)v0.y)));
        atomicMin(m0p + 3, f2ord(b2f((unsigned short)(v0.y >> 16))));
    }
    __syncthreads();
    // epilogue: out = C - min for the bucket's 128 nodes
    for (int sl = t; sl < 128 * 16; sl += 512) {
        const int row = sl >> 4;
        const int node = node0 + row;
        if (node >= N_NODES) break;                    // sl monotone per thread
        const int f4 = (sl & 15) << 2;
        const unsigned* mp = &mn[row * 64 + f4];
        float m0 = ord2f(mp[0]), m1 = ord2f(mp[1]);
        float m2 = ord2f(mp[2]), m3 = ord2f(mp[3]);
        if (fp32mode) {
            float4* C = (float4*)((float*)outv + node * D + f4);
            float4 c = *C;
            *C = make_float4(c.x - m0, c.y - m1, c.z - m2, c.w - m3);
        } else {
            unsigned short* C = (unsigned short*)outv + node * D + f4;
            uint2 c = *(uint2*)C;
            unsigned lo = (unsigned)f2b(b2f((unsigned short)c.x) - m0)
                        | ((unsigned)f2b(b2f((unsigned short)(c.x >> 16)) - m1) << 16);
            unsigned hi = (unsigned)f2b(b2f((unsigned short)c.y) - m2)
                        | ((unsigned)f2b(b2f((unsigned short)(c.y >> 16)) - m3) << 16);
            *(uint2*)C = make_uint2(lo, hi);
        }
    }
}

extern "C" void kernel_launch(void* const* d_in, const int* in_sizes, int n_in,
                              void* d_out, int out_size, void* d_ws, size_t ws_size,
                              hipStream_t stream) {
    // ws layout (~12.8 MB used; ws is ~256 MB):
    char* p = (char*)d_ws;
    unsigned*       flags    = (unsigned*)p;                     // 256 B
    unsigned*       c_cur    = (unsigned*)(p + 256);             // 391*4 -> pad 4096
    unsigned*       packed   = (unsigned*)(p + 4352);            // 391*4096*4 = 6.41 MB
    unsigned short* T16      = (unsigned short*)(p + 4352 + 6406144);   // 6.4 MB
    unsigned short* WTfrag   = (unsigned short*)(p + 4352 + 6406144 + 6400000);        // 8 KB
    unsigned short* WPfrag   = (unsigned short*)(p + 4352 + 6406144 + 6400000 + 8192); // 8 KB
    float*          bias_sum = (float*)(p + 4352 + 6406144 + 6400000 + 16384);         // 256 B

    hipMemsetAsync(c_cur, 0, NB * sizeof(unsigned), stream);
    setup<<<1, 256, 0, stream>>>(d_in[0], d_in[1], d_in[3], d_in[4], d_in[5], d_in[6],
                                 flags, WTfrag, WPfrag, bias_sum);
    gemm_scatter<<<GEMM_BLKS + NSC, 256, 0, stream>>>(d_in[0], WTfrag, WPfrag, bias_sum,
                                                      d_in[1], d_in[2], flags,
                                                      c_cur, packed, T16, d_out);
    bucket_min<<<NB, 512, 0, stream>>>(c_cur, packed, T16, flags, d_out);
}

// Round 16
// 128.356 us; speedup vs baseline: 1.1615x; 1.0568x over previous
//
#include <hip/hip_runtime.h>
#include <hip/hip_bf16.h>

#define N_NODES 50000
#define N_EDGES 800000
#define D 64
#define NB 391        // coarse buckets: dst>>7 -> 0..390 (128 nodes/bucket)
#define BCAP 4096     // fixed slots per bucket region (max load ~2100)
#define CHUNK_E 2048  // edges per scatter block
#define NSC 391       // ceil(800000/2048)
#define NSTRIP 3125   // N_NODES/16
#define GEMM_BLKS 196 // 196*4 waves * 4 strips = 3136 >= NSTRIP
#define NWAVES 784    // gemm waves
#define SPW 4         // strips per wave

typedef __attribute__((ext_vector_type(8))) short short8v;   // 8 bf16 (4 VGPRs)
typedef __attribute__((ext_vector_type(4))) float float4v;   // 4 fp32 acc

// ---------- helpers ----------
__device__ __forceinline__ float b2f(unsigned short h) {
    return __uint_as_float(((unsigned)h) << 16);
}
__device__ __forceinline__ unsigned short f2b(float f) {
    __hip_bfloat16 t = __float2bfloat16(f);
    return *reinterpret_cast<unsigned short*>(&t);
}
__device__ __forceinline__ short f2bs(float f) { return (short)f2b(f); }
// monotonic float<->uint encoding: unsigned min == float min
__device__ __forceinline__ unsigned f2ord(float f) {
    unsigned u = __float_as_uint(f);
    return (u & 0x80000000u) ? ~u : (u | 0x80000000u);
}
__device__ __forceinline__ float ord2f(unsigned o) {
    return __uint_as_float((o & 0x80000000u) ? (o ^ 0x80000000u) : ~o);
}

// ---------- kernel 1: setup (1 block): flags, W->bf16 W^T frags, bias, zero c_cur
__global__ __launch_bounds__(256)
void setup(const void* __restrict__ featv, const void* __restrict__ srcv,
           const void* __restrict__ Wtv, const void* __restrict__ btv,
           const void* __restrict__ Wpv, const void* __restrict__ bpv,
           unsigned* __restrict__ flags, unsigned* __restrict__ c_cur,
           unsigned short* __restrict__ WTfrag, unsigned short* __restrict__ WPfrag,
           float* __restrict__ bias_sum) {
    __shared__ unsigned sf[2];
    const int t = threadIdx.x;
    if (t < 64) {
        const unsigned short* p = (const unsigned short*)featv;
        float x = b2f(p[2 * t]);
        float a = fabsf(x);
        bool insane = !(a <= 64.f) || (x != 0.f && a < 9.3132e-10f);
        unsigned long long m = __ballot(insane);
        if (t == 0) sf[0] = (__popcll(m) >= 8) ? 1u : 0u;
    } else if (t < 128) {
        const int* s32 = (const int*)srcv;
        int v = s32[2 * (t - 64) + 1];
        unsigned long long m = __ballot(v == 0);
        if (t == 64) sf[1] = (__popcll(m) >= 32) ? 1u : 0u;
    }
    __syncthreads();
    const unsigned fp32mode = sf[0];
    if (t < 2) flags[t] = sf[t];
    for (int i = t; i < NB; i += 256) c_cur[i] = 0;     // replaces memsetAsync
#pragma unroll
    for (int i = 0; i < 16; ++i) {
        int e = i * 256 + t;                           // coalesced read
        int k = e >> 6, n = e & 63;
        float vt, vp;
        if (fp32mode) {
            vt = ((const float*)Wtv)[e];
            vp = ((const float*)Wpv)[e];
        } else {
            vt = b2f(((const unsigned short*)Wtv)[e]);
            vp = b2f(((const unsigned short*)Wpv)[e]);
        }
        WTfrag[n * 64 + k] = f2b(vt);                  // Wfrag[n*64+k] = W[k][n]
        WPfrag[n * 64 + k] = f2b(vp);
    }
    if (t < 64) {
        if (fp32mode)
            bias_sum[t] = ((const float*)btv)[t] + ((const float*)bpv)[t];
        else
            bias_sum[t] = b2f(((const unsigned short*)btv)[t])
                        + b2f(((const unsigned short*)bpv)[t]);
    }
}

// ---------- A-fragment load helpers (strip w, lane m,q) ----------
__device__ __forceinline__ void loadA_bf16(const short* F, int w, int m, int q,
                                           short8v& A0, short8v& A1) {
    const short* fr = F + (w * 16 + m) * D + q * 8;
    A0 = *(const short8v*)fr;
    A1 = *(const short8v*)(fr + 32);
}
__device__ __forceinline__ void loadA_raw(const float* F, int w, int m, int q,
                                          float4 r[8]) {
    const float* fr = F + (w * 16 + m) * D + q * 8;
    r[0] = *(const float4*)(fr);      r[1] = *(const float4*)(fr + 4);
    r[2] = *(const float4*)(fr + 32); r[3] = *(const float4*)(fr + 36);
}
__device__ __forceinline__ void cvtA(const float4 r[8], short8v& A0, short8v& A1) {
    A0 = (short8v){f2bs(r[0].x), f2bs(r[0].y), f2bs(r[0].z), f2bs(r[0].w),
                   f2bs(r[1].x), f2bs(r[1].y), f2bs(r[1].z), f2bs(r[1].w)};
    A1 = (short8v){f2bs(r[2].x), f2bs(r[2].y), f2bs(r[2].z), f2bs(r[2].w),
                   f2bs(r[3].x), f2bs(r[3].y), f2bs(r[3].z), f2bs(r[3].w)};
}

// ---------- kernel 2: fused [MFMA node transforms ∥ bucket append] ----------
// gemm blocks [0, GEMM_BLKS): 4 strips/wave, B-frags hoisted (strip-invariant),
//   A software-pipelined (prefetch strip s+1 while computing strip s).
// blocks [GEMM_BLKS, +NSC): append (dst<<16|src) into fixed-stride bucket
//   regions via per-(block,bucket) cursor reservation. Self-loops dropped.
__global__ __launch_bounds__(256)
void gemm_scatter(const void* __restrict__ featv,
                  const unsigned short* __restrict__ WTfrag,
                  const unsigned short* __restrict__ WPfrag,
                  const float* __restrict__ bias_sum,
                  const void* __restrict__ srcv, const void* __restrict__ dstv,
                  const unsigned* __restrict__ flags,
                  unsigned* __restrict__ c_cur, unsigned* __restrict__ packed,
                  unsigned short* __restrict__ T16, void* __restrict__ outv) {
    const unsigned fp32mode = flags[0];
    if (blockIdx.x < GEMM_BLKS) {
        const int lane = threadIdx.x & 63;
        const int wid  = threadIdx.x >> 6;
        const int wave = blockIdx.x * 4 + wid;         // 0..783
        const int m = lane & 15, q = lane >> 4;

        // hoist all 16 B-frags + bias (strip-invariant; L2-hot 16 KB)
        const short8v* BT = (const short8v*)WTfrag;    // idx = col*8 + h*4 + q
        const short8v* BP = (const short8v*)WPfrag;
        short8v Bt0[4], Bt1[4], Bp0[4], Bp1[4];
        float bsv[4];
#pragma unroll
        for (int c = 0; c < 4; ++c) {
            const int col = 16 * c + m;
            Bt0[c] = BT[col * 8 + q];
            Bt1[c] = BT[col * 8 + 4 + q];
            Bp0[c] = BP[col * 8 + q];
            Bp1[c] = BP[col * 8 + 4 + q];
            bsv[c] = bias_sum[col];
        }

        float* Cf  = (float*)outv;
        unsigned short* Ch = (unsigned short*)outv;
        const float* Ff = (const float*)featv;
        const short* Fh = (const short*)featv;

        // software pipeline: load A for strip s+1 while computing strip s
        short8v A0, A1;
        float4 raw[8];
        int w = wave;                                  // strip s=0
        if (fp32mode) { loadA_raw(Ff, min(w, NSTRIP - 1), m, q, raw); cvtA(raw, A0, A1); }
        else          loadA_bf16(Fh, min(w, NSTRIP - 1), m, q, A0, A1);

#pragma unroll
        for (int s = 0; s < SPW; ++s) {
            const int wn = wave + (s + 1) * NWAVES;    // next strip (prefetch)
            if (s + 1 < SPW) {
                if (fp32mode) loadA_raw(Ff, min(wn, NSTRIP - 1), m, q, raw);
                else          loadA_bf16(Fh, min(wn, NSTRIP - 1), m, q, A0, A1);
            }
            // NOTE: bf16 path overwrote A0/A1 — recompute current from w before
            // use would be wrong; so for bf16 keep separate next regs:
            // (handled below by computing with Acur)
            // -- to keep both paths uniform, stash current:
            // (compiler keeps these in regs)
            if (w < NSTRIP) {
                short8v Acur0, Acur1;
                if (s + 1 < SPW && !fp32mode) {
                    // A0/A1 now hold NEXT; reload current cheaply from L1/L2
                    loadA_bf16(Fh, w, m, q, Acur0, Acur1);
                } else if (!fp32mode) {
                    Acur0 = A0; Acur1 = A1;
                } else {
                    Acur0 = A0; Acur1 = A1;            // fp32: A holds current
                }
#pragma unroll
                for (int c = 0; c < 4; ++c) {
                    float4v accT = (float4v){0.f, 0.f, 0.f, 0.f};
                    float4v accP = (float4v){bsv[c], bsv[c], bsv[c], bsv[c]};
                    accT = __builtin_amdgcn_mfma_f32_16x16x32_bf16(Acur0, Bt0[c], accT, 0, 0, 0);
                    accT = __builtin_amdgcn_mfma_f32_16x16x32_bf16(Acur1, Bt1[c], accT, 0, 0, 0);
                    accP = __builtin_amdgcn_mfma_f32_16x16x32_bf16(Acur0, Bp0[c], accP, 0, 0, 0);
                    accP = __builtin_amdgcn_mfma_f32_16x16x32_bf16(Acur1, Bp1[c], accP, 0, 0, 0);
                    // C/D layout: col = lane&15 (+16c), row = q*4 + reg
                    const int col = 16 * c + m;
#pragma unroll
                    for (int r = 0; r < 4; ++r) {
                        const int row = w * 16 + q * 4 + r;
                        T16[row * D + col] = f2b(accT[r]);
                        if (fp32mode) Cf[row * D + col] = accT[r] + accP[r];
                        else          Ch[row * D + col] = f2b(accT[r] + accP[r]);
                    }
                }
            }
            w = wn;
            if (fp32mode && s + 1 < SPW) cvtA(raw, A0, A1);  // convert prefetched
        }
    } else {
        // ---- bucket append branch ----
        __shared__ unsigned h[NB];
        const int t = threadIdx.x;
        for (int i = t; i < NB; i += 256) h[i] = 0;
        __syncthreads();
        const unsigned idx64 = flags[1];
        const int base = (blockIdx.x - GEMM_BLKS) * CHUNK_E;
        unsigned pk[CHUNK_E / 256];
#pragma unroll
        for (int j = 0; j < CHUNK_E / 256; ++j) {
            int e = base + j * 256 + t;
            unsigned p = 0xFFFFFFFFu;                  // sentinel
            if (e < N_EDGES) {
                int s, d;
                if (idx64) {
                    s = (int)((const long long*)srcv)[e];
                    d = (int)((const long long*)dstv)[e];
                } else {
                    s = ((const int*)srcv)[e];
                    d = ((const int*)dstv)[e];
                }
                s = min(max(s, 0), N_NODES - 1);
                d = min(max(d, 0), N_NODES - 1);
                if (s != d) {                          // self-loops seeded in k3
                    p = ((unsigned)d << 16) | (unsigned)s;
                    atomicAdd(&h[d >> 7], 1u);
                }
            }
            pk[j] = p;
        }
        __syncthreads();
        // one reservation atomic per (block,bucket); h becomes the LDS cursor
        for (int i = t; i < NB; i += 256) h[i] = atomicAdd(&c_cur[i], h[i]);
        __syncthreads();
#pragma unroll
        for (int j = 0; j < CHUNK_E / 256; ++j) {
            unsigned p = pk[j];
            if (p != 0xFFFFFFFFu) {
                unsigned bkt = p >> 23;                // == dst>>7
                unsigned pos = atomicAdd(&h[bkt], 1u);
                if (pos < BCAP)                        // overflow guard (never hits)
                    packed[bkt * BCAP + pos] = p;
            }
        }
    }
}

// ---------- kernel 3: per-bucket LDS-atomic min + fused epilogue ----------
// One block per bucket of 128 nodes. mn[128][64] ord-u32 minima in LDS (32 KB),
// seeded with each node's own T row (covers self-loops). 4 gathers in flight.
__global__ __launch_bounds__(512)
void bucket_min(const unsigned* __restrict__ c_cur, const unsigned* __restrict__ packed,
                const unsigned short* __restrict__ T16, const unsigned* __restrict__ flags,
                void* __restrict__ outv) {
    __shared__ unsigned mn[128 * 64];                  // 32 KB
    const unsigned fp32mode = flags[0];
    const int t = threadIdx.x;
    const int b = blockIdx.x;
    const int node0 = b << 7;
    // seed with own-node T rows (coalesced 16 KB; covers self-loop edges)
    for (int sl = t; sl < 128 * 16; sl += 512) {
        const int row = sl >> 4;
        const int f4 = (sl & 15) << 2;
        unsigned* mp = &mn[row * 64 + f4];
        if (node0 + row < N_NODES) {
            uint2 v = *(const uint2*)(T16 + (node0 + row) * D + f4);
            mp[0] = f2ord(b2f((unsigned short)v.x));
            mp[1] = f2ord(b2f((unsigned short)(v.x >> 16)));
            mp[2] = f2ord(b2f((unsigned short)v.y));
            mp[3] = f2ord(b2f((unsigned short)(v.y >> 16)));
        } else {
            mp[0] = mp[1] = mp[2] = mp[3] = 0xFFFFFFFFu;
        }
    }
    __syncthreads();
    const int cnt = min((int)c_cur[b], BCAP);
    const unsigned* pb = packed + b * BCAP;
    const int lane = t & 63, wv = t >> 6;              // 8 waves
    const int g = lane >> 4, fb = (lane & 15) << 2;    // 4 edges x 16 feature-quads
    int i = wv * 4 + g;
    for (; i + 96 < cnt; i += 128) {                   // 4 gathers in flight
        unsigned p0 = pb[i],      p1 = pb[i + 32];
        unsigned p2 = pb[i + 64], p3 = pb[i + 96];
        uint2 v0 = *(const uint2*)(T16 + (int)(p0 & 0xFFFFu) * D + fb);
        uint2 v1 = *(const uint2*)(T16 + (int)(p1 & 0xFFFFu) * D + fb);
        uint2 v2 = *(const uint2*)(T16 + (int)(p2 & 0xFFFFu) * D + fb);
        uint2 v3 = *(const uint2*)(T16 + (int)(p3 & 0xFFFFu) * D + fb);
        unsigned* m0p = &mn[(int)((p0 >> 16) & 127u) * 64 + fb];
        unsigned* m1p = &mn[(int)((p1 >> 16) & 127u) * 64 + fb];
        unsigned* m2p = &mn[(int)((p2 >> 16) & 127u) * 64 + fb];
        unsigned* m3p = &mn[(int)((p3 >> 16) & 127u) * 64 + fb];
        atomicMin(m0p + 0, f2ord(b2f((unsigned short)v0.x)));
        atomicMin(m0p + 1, f2ord(b2f((unsigned short)(v0.x >> 16))));
        atomicMin(m0p + 2, f2ord(b2f((unsigned short)v0.y)));
        atomicMin(m0p + 3, f2ord(b2f((unsigned short)(v0.y >> 16))));
        atomicMin(m1p + 0, f2ord(b2f((unsigned short)v1.x)));
        atomicMin(m1p + 1, f2ord(b2f((unsigned short)(v1.x >> 16))));
        atomicMin(m1p + 2, f2ord(b2f((unsigned short)v1.y)));
        atomicMin(m1p + 3, f2ord(b2f((unsigned short)(v1.y >> 16))));
        atomicMin(m2p + 0, f2ord(b2f((unsigned short)v2.x)));
        atomicMin(m2p + 1, f2ord(b2f((unsigned short)(v2.x >> 16))));
        atomicMin(m2p + 2, f2ord(b2f((unsigned short)v2.y)));
        atomicMin(m2p + 3, f2ord(b2f((unsigned short)(v2.y >> 16))));
        atomicMin(m3p + 0, f2ord(b2f((unsigned short)v3.x)));
        atomicMin(m3p + 1, f2ord(b2f((unsigned short)(v3.x >> 16))));
        atomicMin(m3p + 2, f2ord(b2f((unsigned short)v3.y)));
        atomicMin(m3p + 3, f2ord(b2f((unsigned short)(v3.y >> 16))));
    }
    for (; i < cnt; i += 32) {
        unsigned p0 = pb[i];
        uint2 v0 = *(const uint2*)(T16 + (int)(p0 & 0xFFFFu) * D + fb);
        unsigned* m0p = &mn[(int)((p0 >> 16) & 127u) * 64 + fb];
        atomicMin(m0p + 0, f2ord(b2f((unsigned short)v0.x)));
        atomicMin(m0p + 1, f2ord(b2f((unsigned short)(v0.x >> 16))));
        atomicMin(m0p + 2, f2ord(b2f((unsigned short)v0.y)));
        atomicMin(m0p + 3, f2ord(b2f((unsigned short)(v0.y >> 16))));
    }
    __syncthreads();
    // epilogue: out = C - min for the bucket's 128 nodes
    for (int sl = t; sl < 128 * 16; sl += 512) {
        const int row = sl >> 4;
        const int node = node0 + row;
        if (node >= N_NODES) break;                    // sl monotone per thread
        const int f4 = (sl & 15) << 2;
        const unsigned* mp = &mn[row * 64 + f4];
        float m0 = ord2f(mp[0]), m1 = ord2f(mp[1]);
        float m2 = ord2f(mp[2]), m3 = ord2f(mp[3]);
        if (fp32mode) {
            float4* C = (float4*)((float*)outv + node * D + f4);
            float4 c = *C;
            *C = make_float4(c.x - m0, c.y - m1, c.z - m2, c.w - m3);
        } else {
            unsigned short* C = (unsigned short*)outv + node * D + f4;
            uint2 c = *(uint2*)C;
            unsigned lo = (unsigned)f2b(b2f((unsigned short)c.x) - m0)
                        | ((unsigned)f2b(b2f((unsigned short)(c.x >> 16)) - m1) << 16);
            unsigned hi = (unsigned)f2b(b2f((unsigned short)c.y) - m2)
                        | ((unsigned)f2b(b2f((unsigned short)(c.y >> 16)) - m3) << 16);
            *(uint2*)C = make_uint2(lo, hi);
        }
    }
}

extern "C" void kernel_launch(void* const* d_in, const int* in_sizes, int n_in,
                              void* d_out, int out_size, void* d_ws, size_t ws_size,
                              hipStream_t stream) {
    // ws layout (~12.8 MB used; ws is ~256 MB):
    char* p = (char*)d_ws;
    unsigned*       flags    = (unsigned*)p;                     // 256 B
    unsigned*       c_cur    = (unsigned*)(p + 256);             // 391*4 -> pad 4096
    unsigned*       packed   = (unsigned*)(p + 4352);            // 391*4096*4 = 6.41 MB
    unsigned short* T16      = (unsigned short*)(p + 4352 + 6406144);   // 6.4 MB
    unsigned short* WTfrag   = (unsigned short*)(p + 4352 + 6406144 + 6400000);        // 8 KB
    unsigned short* WPfrag   = (unsigned short*)(p + 4352 + 6406144 + 6400000 + 8192); // 8 KB
    float*          bias_sum = (float*)(p + 4352 + 6406144 + 6400000 + 16384);         // 256 B

    setup<<<1, 256, 0, stream>>>(d_in[0], d_in[1], d_in[3], d_in[4], d_in[5], d_in[6],
                                 flags, c_cur, WTfrag, WPfrag, bias_sum);
    gemm_scatter<<<GEMM_BLKS + NSC, 256, 0, stream>>>(d_in[0], WTfrag, WPfrag, bias_sum,
                                                      d_in[1], d_in[2], flags,
                                                      c_cur, packed, T16, d_out);
    bucket_min<<<NB, 512, 0, stream>>>(c_cur, packed, T16, flags, d_out);
}